// Round 8
// baseline (75.060 us; speedup 1.0000x reference)
//
#include <hip/hip_runtime.h>
#include <hip/hip_bf16.h>

#define F_   512
#define FF_  (512 * 512)
#define C_   128

typedef __attribute__((ext_vector_type(4))) float f32x4;
typedef __attribute__((ext_vector_type(8))) short s16x8;
typedef __attribute__((ext_vector_type(4))) unsigned short u16x4;

__device__ __forceinline__ unsigned short f2bf(float f) {
    union { __hip_bfloat16 h; unsigned short u; } c;
    c.h = __float2bfloat16(f);
    return c.u;
}

__device__ __forceinline__ s16x8 pack8(f32x4 lo, f32x4 hi) {
    s16x8 r;
    r[0] = (short)f2bf(lo[0]); r[1] = (short)f2bf(lo[1]);
    r[2] = (short)f2bf(lo[2]); r[3] = (short)f2bf(lo[3]);
    r[4] = (short)f2bf(hi[0]); r[5] = (short)f2bf(hi[1]);
    r[6] = (short)f2bf(hi[2]); r[7] = (short)f2bf(hi[3]);
    return r;
}

#define GLDS16(gp, lp)                                                         \
    __builtin_amdgcn_global_load_lds(                                          \
        (const __attribute__((address_space(1))) void*)(gp),                   \
        (__attribute__((address_space(3))) void*)(lp), 16, 0, 0)

// ---------------------------------------------------------------------------
// Kernel 0: pre-pack phi -> per-(bt,kk,lane) bf16 MFMA N-side fragments.
// ---------------------------------------------------------------------------
__global__ __launch_bounds__(256) void k0_prepack(
    const float* __restrict__ phi, unsigned short* __restrict__ phiP)
{
    const int t = threadIdx.x;
#pragma unroll
    for (int j = 0; j < 4; ++j) {
        int e = (j << 8) + t;               // 0..1023
        int lane = e & 63, mk = e >> 6;
        int m = mk >> 2, kk = mk & 3;
        int brow = lane & 15, quad = lane >> 4;
        const float* p = phi + ((m << 4) + brow) * C_ + kk * 32 + (quad << 3);
        s16x8 v = pack8(*(const f32x4*)p, *(const f32x4*)(p + 4));
        *(s16x8*)&phiP[e << 3] = v;
    }
}

// ---------------------------------------------------------------------------
// Kernel 1 v10: FULL-LINE stores. Block = 64i x 8k x 64b (512 blocks, 2/CU).
// Per k-iter: 4 waves share one 32KB staged A-tile (each stages its 16 rows,
// contiguous 1KB glds, source XOR-swizzled 16B granule); operand-swapped
// MFMA (M=i-cells, N=b): wave owns one 16-b tile x 64 i = 16 MFMA/iter.
// Wave-private 2.5KB trans regroups 4-i runs -> 8-i runs; stores = 2 x 1KB
// insts = 8 full 128B lines each, ZERO partial-line writes. One raw
// s_barrier/iter + counted vmcnt(2) (prefetch never drained). Masked rows
// staged via dup-address (L1 hit); fully-masked m-tiles skip compute.
// Blocks 512+: bias rows.
// ---------------------------------------------------------------------------
__global__ __launch_bounds__(256, 2) void k1_params(
    const unsigned short* __restrict__ phiP, const float* __restrict__ Wc,
    const float* __restrict__ bc, unsigned short* __restrict__ wT,
    float* __restrict__ biasWS, const float* __restrict__ phi)
{
    const int blk = blockIdx.x;
    const int tid = threadIdx.x;

    if (blk >= 512) {                       // ---- bias part ----
        int g = ((blk - 512) << 8) + tid;   // 0..32767
        int k = g >> 6, b = g & 63;
        const f32x4* w4 = (const f32x4*)(Wc + (size_t)(FF_ + k) * C_);
        const f32x4* p4 = (const f32x4*)(phi + b * C_);
        float acc = bc[FF_ + k];
#pragma unroll
        for (int c = 0; c < 32; ++c) {
            f32x4 a = w4[c], q = p4[c];
            acc += a[0]*q[0] + a[1]*q[1] + a[2]*q[2] + a[3]*q[3];
        }
        biasWS[(b << 9) + k] = acc;
        return;
    }

    __shared__ __align__(16) char stg[2][32768];            // 64 KB dbuf
    __shared__ __align__(16) unsigned short trans[4][1280]; // 4 x 2.5 KB
    __shared__ float bcs[64 * 9];                           // 2.3 KB (pad 9)

    const int lane = tid & 63, wave = tid >> 6, quad = lane >> 4;
    const int i0 = (blk >> 6) << 6;      // 8 i-groups of 64
    const int k0 = (blk & 63) << 3;      // 64 k-octets

    // ---- bcs: bc slice [64 i][8 k] -> LDS (stride 9 kills quad-bank clash)
    {
        int il = tid >> 2, kp = (tid & 3) << 1;
        const float* s = bc + (size_t)(i0 + il) * F_ + k0 + kp;
        bcs[il * 9 + kp]     = s[0];
        bcs[il * 9 + kp + 1] = s[1];
    }

    // ---- phi N-frags for this wave's 16-b tile (16 VGPR)
    s16x8 bfr[4];
#pragma unroll
    for (int kk = 0; kk < 4; ++kk)
        bfr[kk] = *(const s16x8*)&phiP[((((wave << 2) + kk) << 6) | lane) << 3];

    // ---- per-lane cell d's + per-mtile wave-uniform max-d
    int dcell[4][4];
#pragma unroll
    for (int mt = 0; mt < 4; ++mt)
#pragma unroll
        for (int rr = 0; rr < 4; ++rr)
            dcell[mt][rr] = (i0 + mt * 16 + (quad << 2) + rr) % 63;
    int dmax[4];
#pragma unroll
    for (int mt = 0; mt < 4; ++mt) {
        int a = (i0 + mt * 16) % 63;
        dmax[mt] = (a + 15 >= 63) ? 62 : a + 15;
    }

    // ---- staging precompute: inst j covers rows wave*16+2j (+lane>>5)
    int irow[8], drow[8], swj[8];
#pragma unroll
    for (int j = 0; j < 8; ++j) {
        int rl = (wave << 4) + (j << 1) + (lane >> 5);
        irow[j] = i0 + rl;
        drow[j] = (i0 + rl) % 63;
        swj[j]  = ((lane & 31) << 4) ^ ((rl & 7) << 4);
    }
    const int idup = i0 + ((62 - (i0 % 63)) + 63) % 63;   // d=62 row (unmasked)

    auto STAGE = [&](int t, int buf) {
        const int k = k0 + t, dk = (k0 + t) % 63;
#pragma unroll
        for (int j = 0; j < 8; ++j) {
            int isel = (drow[j] >= dk) ? irow[j] : idup;
            const char* src = (const char*)Wc
                            + ((size_t)(isel * F_ + k) << 9) + swj[j];
            GLDS16(src, stg[buf] + (((wave << 4) + (j << 1)) << 9));
        }
    };

    STAGE(0, 0);
    __syncthreads();     // drains prologue (incl STAGE 0), bcs visible

    const int swz = (lane & 7) << 4;

#pragma unroll
    for (int t = 0; t < 8; ++t) {
        if (t < 7) STAGE(t + 1, (t + 1) & 1);

        const int dk = (k0 + t) % 63;
        const char* sb = stg[t & 1];
        unsigned short* trw = trans[wave];

#pragma unroll
        for (int mt = 0; mt < 4; ++mt) {
            const int tpos = ((lane & 15) * 160
                           + ((mt * 32 + (quad << 3)) ^ swz)) >> 1; // u16 idx
            if (dmax[mt] >= dk) {
                f32x4 acc = (f32x4){0.f, 0.f, 0.f, 0.f};
                const char* rowb = sb + ((mt * 16 + (lane & 15)) << 9);
#pragma unroll
                for (int kk = 0; kk < 4; ++kk) {
                    int x = ((kk << 7) + (quad << 5)) ^ swz;
                    f32x4 lo = *(const f32x4*)(rowb + x);
                    f32x4 hi = *(const f32x4*)(rowb + (x ^ 16));
                    acc = __builtin_amdgcn_mfma_f32_16x16x32_bf16(
                        pack8(lo, hi), bfr[kk], acc, 0, 0, 0);
                }
                u16x4 v;
#pragma unroll
                for (int rr = 0; rr < 4; ++rr) {
                    float bv = bcs[(mt * 16 + (quad << 2) + rr) * 9 + t];
                    v[rr] = (dcell[mt][rr] >= dk)
                          ? f2bf(acc[rr] + bv) : (unsigned short)0;
                }
                *(u16x4*)&trw[tpos] = v;
            } else {
                *(u16x4*)&trw[tpos] = (u16x4){0, 0, 0, 0};
            }
        }

        // ---- readback + FULL-LINE stores: 2 insts x 1KB (8 lines each)
#pragma unroll
        for (int h = 0; h < 2; ++h) {
            int bl = (h << 3) + (lane >> 3), r = lane & 7;
            int rr2 = r ^ (bl & 7);
            s16x8 v = *(const s16x8*)&trw[bl * 80 + (rr2 << 3)];
            unsigned short* dst = wT
                + (((size_t)(((wave << 4) + bl) << 9) + k0 + t) << 9)
                + i0 + (r << 3);
            *(s16x8*)dst = v;
        }

        if (t < 7) {
            asm volatile("s_waitcnt vmcnt(2)" ::: "memory");
            __builtin_amdgcn_s_barrier();
        }
    }
}

// ---------------------------------------------------------------------------
// Kernel 2 (unchanged): two chained GEMMs vs wT + bias, residual epilogue.
// ---------------------------------------------------------------------------
#define SMEM_BOFF 66560           // 64*1040
#define CHUNK_B   32768
#define SMEM_TOT  (66560 + 2 * 32768)   // 132096

__global__ __launch_bounds__(512) void k2_apply(
    const float* __restrict__ X, const unsigned short* __restrict__ wT,
    const float* __restrict__ biasWS, float* __restrict__ out)
{
    extern __shared__ char smem[];
    unsigned short* A_lds = (unsigned short*)smem;

    const int blk = blockIdx.x;
    const int sw  = ((blk & 7) << 5) + (blk >> 3);   // XCD swizzle
    const int b   = sw >> 2;
    const int n0  = (sw & 3) << 6;

    const int tid = threadIdx.x, lane = tid & 63, wave = tid >> 6;
    const int wn = wave >> 2, wk = wave & 3;

    const float* Xb = X + (((size_t)(b * 256 + n0)) << 9);
    float*       Ob = out + (((size_t)(b * 256 + n0)) << 9);
    const unsigned short* wTb = wT + ((size_t)b << 18);

    float biasr[8];
#pragma unroll
    for (int nt = 0; nt < 8; ++nt)
        biasr[nt] = biasWS[(b << 9) + (wk << 7) + (nt << 4) + (lane & 15)];

    {
        const f32x4* X4 = (const f32x4*)Xb;
#pragma unroll
        for (int j = 0; j < 16; ++j) {
            int f = (j << 9) + tid;
            int row = f >> 7, c4 = f & 127;
            f32x4 v = X4[f];
            u16x4 h;
#pragma unroll
            for (int e = 0; e < 4; ++e) h[e] = f2bf(fmaxf(v[e], 0.f));
            *(u16x4*)&A_lds[row * 520 + (c4 << 2)] = h;
        }
    }

    const int srcslot = ((lane & 3) ^ ((lane >> 3) & 3)) << 3;

    f32x4 acc[2][8];

    for (int phase = 0; phase < 2; ++phase) {
#pragma unroll
        for (int mt = 0; mt < 2; ++mt)
#pragma unroll
            for (int nt = 0; nt < 8; ++nt) acc[mt][nt] = (f32x4){0.f, 0.f, 0.f, 0.f};

#pragma unroll
        for (int g = 0; g < 4; ++g) {
            int krow = (wave << 6) + (g << 4) + (lane >> 2);
            const unsigned short* src = wTb + ((size_t)krow << 9) + srcslot;
            char* lp = smem + SMEM_BOFF + (((wave << 6) + (g << 4)) << 6);
            GLDS16(src, lp);
        }
        asm volatile("s_waitcnt vmcnt(0)" ::: "memory");
        __syncthreads();

        for (int c = 0; c < 16; ++c) {
            const int cur = c & 1;
            if (c < 15) {
                const int i0n = (c + 1) << 5;
#pragma unroll
                for (int g = 0; g < 4; ++g) {
                    int krow = (wave << 6) + (g << 4) + (lane >> 2);
                    const unsigned short* src = wTb + ((size_t)krow << 9) + i0n + srcslot;
                    char* lp = smem + SMEM_BOFF + (cur ^ 1) * CHUNK_B
                             + (((wave << 6) + (g << 4)) << 6);
                    GLDS16(src, lp);
                }
            }
            const int i0c = c << 5;
            s16x8 afr[2];
#pragma unroll
            for (int mt = 0; mt < 2; ++mt) {
                int n = (wn << 5) + (mt << 4) + (lane & 15);
                afr[mt] = *(const s16x8*)&A_lds[n * 520 + i0c + ((lane >> 4) << 3)];
            }
            const unsigned short* Bb =
                (const unsigned short*)(smem + SMEM_BOFF + cur * CHUNK_B);
#pragma unroll
            for (int nt = 0; nt < 8; ++nt) {
                int k = (wk << 7) + (nt << 4) + (lane & 15);
                int slot = (((lane >> 4) ^ ((k >> 1) & 3)) << 3);
                s16x8 bfr = *(const s16x8*)&Bb[(k << 5) + slot];
#pragma unroll
                for (int mt = 0; mt < 2; ++mt)
                    acc[mt][nt] = __builtin_amdgcn_mfma_f32_16x16x32_bf16(
                        afr[mt], bfr, acc[mt][nt], 0, 0, 0);
            }
            asm volatile("s_waitcnt vmcnt(0)" ::: "memory");
            __syncthreads();
        }

        if (phase == 0) {
#pragma unroll
            for (int mt = 0; mt < 2; ++mt)
#pragma unroll
                for (int nt = 0; nt < 8; ++nt) {
                    int k = (wk << 7) + (nt << 4) + (lane & 15);
#pragma unroll
                    for (int r = 0; r < 4; ++r) {
                        int n = (wn << 5) + (mt << 4) + ((lane >> 4) << 2) + r;
                        A_lds[n * 520 + k] =
                            f2bf(fmaxf(acc[mt][nt][r] + biasr[nt], 0.f));
                    }
                }
            __syncthreads();
        }
    }

#pragma unroll
    for (int mt = 0; mt < 2; ++mt)
#pragma unroll
        for (int nt = 0; nt < 8; ++nt) {
            int k = (wk << 7) + (nt << 4) + (lane & 15);
#pragma unroll
            for (int r = 0; r < 4; ++r) {
                int n = (wn << 5) + (mt << 4) + ((lane >> 4) << 2) + r;
                size_t off = ((size_t)n << 9) + k;
                Ob[off] = Xb[off] + acc[mt][nt][r] + biasr[nt];
            }
        }
}

extern "C" void kernel_launch(void* const* d_in, const int* in_sizes, int n_in,
                              void* d_out, int out_size, void* d_ws, size_t ws_size,
                              hipStream_t stream) {
    const float* inputs = (const float*)d_in[0];
    const float* phi    = (const float*)d_in[1];
    const float* Wc     = (const float*)d_in[2];
    const float* bc     = (const float*)d_in[3];
    float* out = (float*)d_out;

    unsigned short* wT = (unsigned short*)d_ws;                          // 32 MiB
    float* biasWS = (float*)((char*)d_ws + (size_t)64 * 512 * 512 * 2);  // 128 KiB
    unsigned short* phiP =
        (unsigned short*)((char*)d_ws + (size_t)64 * 512 * 512 * 2 + 64 * 512 * 4);

    hipLaunchKernelGGL(k0_prepack, dim3(1), dim3(256), 0, stream, phi, phiP);

    hipLaunchKernelGGL(k1_params, dim3(640), dim3(256), 0, stream,
                       phiP, Wc, bc, wT, biasWS, phi);

    hipFuncSetAttribute((const void*)k2_apply,
                        hipFuncAttributeMaxDynamicSharedMemorySize, SMEM_TOT);
    hipLaunchKernelGGL(k2_apply, dim3(256), dim3(512), SMEM_TOT, stream,
                       inputs, wT, biasWS, out);
}